// Round 7
// baseline (261.012 us; speedup 1.0000x reference)
//
#include <hip/hip_runtime.h>
#include <hip/hip_bf16.h>

#define NN 8192
#define LOG2E 1.44269504088896f

typedef __attribute__((ext_vector_type(8))) short short8;
typedef __attribute__((ext_vector_type(4))) float f32x4;

static __device__ __forceinline__ float bf2f(unsigned short u) {
    union { unsigned int i; float f; } v; v.i = ((unsigned int)u) << 16; return v.f;
}
static __device__ __forceinline__ unsigned short f2bf(float f) {
    union { float f; unsigned int i; } v; v.f = f;
    unsigned int lsb = (v.i >> 16) & 1u;
    v.i += 0x7fffu + lsb;
    return (unsigned short)(v.i >> 16);
}
static __device__ __forceinline__ unsigned int cvtpk(float lo, float hi) {
    unsigned int r;
    asm("v_cvt_pk_bf16_f32 %0, %1, %2" : "=v"(r) : "v"(lo), "v"(hi));
    return r;
}
static __device__ __forceinline__ float fexp2(float x) { return __builtin_amdgcn_exp2f(x); }

static __device__ __forceinline__ void cvt8(const float* __restrict__ p, short8& hi, short8& lo) {
    float4 u = *(const float4*)p;
    float4 v = *(const float4*)(p + 4);
    float f[8] = {u.x, u.y, u.z, u.w, v.x, v.y, v.z, v.w};
#pragma unroll
    for (int j = 0; j < 8; ++j) {
        unsigned short hb = f2bf(f[j]);
        hi[j] = (short)hb;
        lo[j] = (short)f2bf(f[j] - bf2f(hb));
    }
}

// ---- prep: v1/v2 (W^T a vectors), split over 16 blocks then reduced ----
__global__ void prep_partial(const float* __restrict__ W1, const float* __restrict__ W2,
                             const float* __restrict__ a,
                             float* __restrict__ v1p, float* __restrict__ v2p) {
    int b = blockIdx.x;
    int t = threadIdx.x;
    int hh = t >> 8, k = t & 255;
    int c0 = (b & 7) * 16;
    const float* W = (b < 8) ? W1 : W2;
    int aoff = (b < 8) ? 0 : 128;
    float acc = 0.f;
    for (int c = c0; c < c0 + 16; ++c)
        acc += W[(size_t)(hh * 128 + c) * 256 + k] * a[hh * 256 + aoff + c];
    ((b < 8) ? v1p : v2p)[(b & 7) * 512 + t] = acc;
}

// 512 threads: v-sum + fully parallel bd (4 dots of 128, one product/thread)
__global__ void prep_reduce(const float* __restrict__ b1, const float* __restrict__ b2,
                            const float* __restrict__ a,
                            const float* __restrict__ v1p, const float* __restrict__ v2p,
                            float* __restrict__ v1, float* __restrict__ v2, float* __restrict__ bd) {
    int t = threadIdx.x;
    float a1 = 0.f, a2 = 0.f;
    for (int b = 0; b < 8; ++b) { a1 += v1p[b * 512 + t]; a2 += v2p[b * 512 + t]; }
    v1[t] = a1;
    v2[t] = a2;
    int g = t >> 7;                      // group 0..3 = bd index (hh*2+which)
    int hh = g >> 1, which = g & 1, c = t & 127;
    float prod = which ? b2[hh * 128 + c] * a[hh * 256 + 128 + c]
                       : b1[hh * 128 + c] * a[hh * 256 + c];
#pragma unroll
    for (int off = 1; off < 64; off <<= 1) prod += __shfl_xor(prod, off);
    __shared__ float ws[8];
    if ((t & 63) == 0) ws[t >> 6] = prod;
    __syncthreads();
    if (t < 4) bd[t] = ws[2 * t] + ws[2 * t + 1];
}

// s1[n][h] interleaved; s2 in per-head PLANES s2h[h][n]. Both pre-scaled by log2(e).
__global__ __launch_bounds__(256) void s_kernel(const float* __restrict__ hmat,
                         const float* __restrict__ v1, const float* __restrict__ v2,
                         const float* __restrict__ bd,
                         float* __restrict__ s1o, float* __restrict__ s2o) {
    int w = threadIdx.x >> 6, l = threadIdx.x & 63;
    int n = blockIdx.x * 4 + w;
    float4 hv  = *(const float4*)(hmat + (size_t)n * 256 + l * 4);
    float4 va0 = *(const float4*)(v1 + l * 4);
    float4 va1 = *(const float4*)(v1 + 256 + l * 4);
    float4 vb0 = *(const float4*)(v2 + l * 4);
    float4 vb1 = *(const float4*)(v2 + 256 + l * 4);
    float s10 = hv.x*va0.x + hv.y*va0.y + hv.z*va0.z + hv.w*va0.w;
    float s11 = hv.x*va1.x + hv.y*va1.y + hv.z*va1.z + hv.w*va1.w;
    float s20 = hv.x*vb0.x + hv.y*vb0.y + hv.z*vb0.z + hv.w*vb0.w;
    float s21 = hv.x*vb1.x + hv.y*vb1.y + hv.z*vb1.z + hv.w*vb1.w;
#pragma unroll
    for (int off = 1; off < 64; off <<= 1) {
        s10 += __shfl_xor(s10, off);
        s11 += __shfl_xor(s11, off);
        s20 += __shfl_xor(s20, off);
        s21 += __shfl_xor(s21, off);
    }
    if (l == 0) {
        s1o[n*2 + 0] = (s10 + bd[0]) * LOG2E;
        s1o[n*2 + 1] = (s11 + bd[2]) * LOG2E;
        s2o[n]       = (s20 + bd[1]) * LOG2E;   // head 0 plane
        s2o[NN + n]  = (s21 + bd[3]) * LOG2E;   // head 1 plane
    }
}

// W3h in MFMA-FRAGMENT-MAJOR layout:
// w3b[((n>>5)*16 + (c>>4))*512 + (((n>>3)&3)*16 + (c&15))*8 + (n&7)]
// => per (j-tile, c-tile) a 1KB block in exact B-frag lane order (lane=kq*16+m, elem=jj).
__global__ __launch_bounds__(128) void w3_kernel(const float* __restrict__ hmat,
                                                 const float* __restrict__ W3,
                                                 const float* __restrict__ b3,
                                                 unsigned short* __restrict__ w3b) {
    int tid = threadIdx.x;
    int w = tid >> 6, l = tid & 63;
    int m = l & 15, kq = l >> 4;
    int n0 = blockIdx.x * 32 + w * 16;
    f32x4 acc[16];
#pragma unroll
    for (int ct = 0; ct < 16; ++ct) acc[ct] = (f32x4){0.f, 0.f, 0.f, 0.f};
    for (int k0 = 0; k0 < 256; k0 += 32) {
        short8 ahi, alo;
        cvt8(hmat + (size_t)(n0 + m) * 256 + k0 + kq * 8, ahi, alo);
#pragma unroll
        for (int ct = 0; ct < 16; ++ct) {
            short8 bhi, blo;
            cvt8(W3 + (size_t)(ct * 16 + m) * 256 + k0 + kq * 8, bhi, blo);
            acc[ct] = __builtin_amdgcn_mfma_f32_16x16x32_bf16(ahi, bhi, acc[ct], 0, 0, 0);
            acc[ct] = __builtin_amdgcn_mfma_f32_16x16x32_bf16(alo, bhi, acc[ct], 0, 0, 0);
            acc[ct] = __builtin_amdgcn_mfma_f32_16x16x32_bf16(ahi, blo, acc[ct], 0, 0, 0);
        }
    }
#pragma unroll
    for (int ct = 0; ct < 16; ++ct) {
        int c = ct * 16 + m;
        float bias = b3[c];
#pragma unroll
        for (int r = 0; r < 4; ++r) {
            int n = n0 + kq * 4 + r;
            size_t idx = ((size_t)(n >> 5) * 16 + ct) * 512 + (size_t)((((n >> 3) & 3) * 16 + m) * 8 + (n & 7));
            w3b[idx] = f2bf(acc[ct][r] + bias);
        }
    }
}

// ---- main fused attention: BARRIER-FREE ----
// 512 threads = 8 independent waves; wave (rg,cg) owns rows i0+rg*32..+32, cols cg*64..+64
// (head hw=cg>>1). Zero LDS, zero s_barrier: P computed in-register per wave, B-frags as
// coalesced 1KB global loads from fragment-major w3b, denominator via all-ones B-frag on
// the matrix pipe. Latency hidden by 16 waves/CU TLP + compiler vmcnt pipelining.
__global__ __launch_bounds__(512, 4) void attn_fused(
        const int* __restrict__ adj, const float* __restrict__ s1a,
        const float* __restrict__ s2h, const unsigned short* __restrict__ w3b,
        unsigned short* __restrict__ pacc, float* __restrict__ pden, int jc)
{
    const int tid = threadIdx.x;
    const int wv = tid >> 6, ln = tid & 63;
    const int m = ln & 15, kq = ln >> 4;
    const int rg = wv & 1, cg = wv >> 1;
    const int hw = cg >> 1;
    const int i0 = blockIdx.x * 64;
    const int sidx = blockIdx.y;
    const int j0 = sidx * jc;
    const int nt = jc >> 5;
    const int rowA = i0 + rg * 32 + m, rowB = rowA + 16;

    const float sA = s1a[rowA * 2 + hw];
    const float sB = s1a[rowB * 2 + hw];
    const int* adjA = adj + (size_t)rowA * NN + j0 + kq * 8;
    const int* adjB = adj + (size_t)rowB * NN + j0 + kq * 8;
    const float* s2p = s2h + (size_t)hw * NN + j0 + kq * 8;
    const unsigned short* w3p = w3b + ((size_t)(j0 >> 5) * 16 + cg * 4) * 512 + ln * 8;

    f32x4 acc[2][4];
    f32x4 accd[2];
#pragma unroll
    for (int rt = 0; rt < 2; ++rt) {
        accd[rt] = (f32x4){0.f, 0.f, 0.f, 0.f};
#pragma unroll
        for (int f = 0; f < 4; ++f) acc[rt][f] = (f32x4){0.f, 0.f, 0.f, 0.f};
    }
    short8 ones;
#pragma unroll
    for (int e = 0; e < 8; ++e) ones[e] = (short)0x3F80;   // bf16 1.0

    // adj prefetch (tile 0)
    int4 cA0 = *(const int4*)adjA, cA1 = *(const int4*)(adjA + 4);
    int4 cB0 = *(const int4*)adjB, cB1 = *(const int4*)(adjB + 4);

    for (int t = 0; t < nt; ++t) {
        const int tn = (t + 1 < nt) ? t + 1 : t;
        // issue next-iter adj early (HBM, ~900cy to hide)
        int4 nA0 = *(const int4*)(adjA + tn * 32), nA1 = *(const int4*)(adjA + tn * 32 + 4);
        int4 nB0 = *(const int4*)(adjB + tn * 32), nB1 = *(const int4*)(adjB + tn * 32 + 4);
        // s2 (L2-resident) + B frags (L2/L3-resident, 1KB coalesced per frag)
        float4 f0 = *(const float4*)(s2p + t * 32);
        float4 f1 = *(const float4*)(s2p + t * 32 + 4);
        const unsigned short* bp = w3p + (size_t)t * 8192;
        // P-gen in-register
        int aj[8] = {cA0.x, cA0.y, cA0.z, cA0.w, cA1.x, cA1.y, cA1.z, cA1.w};
        int bj[8] = {cB0.x, cB0.y, cB0.z, cB0.w, cB1.x, cB1.y, cB1.z, cB1.w};
        float fj[8] = {f0.x, f0.y, f0.z, f0.w, f1.x, f1.y, f1.z, f1.w};
        union { short8 v; unsigned int u[4]; } Ua, Ub;
#pragma unroll
        for (int q = 0; q < 4; ++q) {
            float x0, x1, p0, p1;
            x0 = sA + fj[2*q];     x0 = fmaxf(x0, 0.2f * x0);
            x1 = sA + fj[2*q+1];   x1 = fmaxf(x1, 0.2f * x1);
            p0 = aj[2*q]   ? fexp2(x0) : 0.f;
            p1 = aj[2*q+1] ? fexp2(x1) : 0.f;
            Ua.u[q] = cvtpk(p0, p1);
            x0 = sB + fj[2*q];     x0 = fmaxf(x0, 0.2f * x0);
            x1 = sB + fj[2*q+1];   x1 = fmaxf(x1, 0.2f * x1);
            p0 = bj[2*q]   ? fexp2(x0) : 0.f;
            p1 = bj[2*q+1] ? fexp2(x1) : 0.f;
            Ub.u[q] = cvtpk(p0, p1);
        }
        __builtin_amdgcn_s_setprio(1);
#pragma unroll
        for (int f = 0; f < 4; ++f) {
            short8 bf = *(const short8*)(bp + f * 512);
            acc[0][f] = __builtin_amdgcn_mfma_f32_16x16x32_bf16(Ua.v, bf, acc[0][f], 0, 0, 0);
            acc[1][f] = __builtin_amdgcn_mfma_f32_16x16x32_bf16(Ub.v, bf, acc[1][f], 0, 0, 0);
        }
        accd[0] = __builtin_amdgcn_mfma_f32_16x16x32_bf16(Ua.v, ones, accd[0], 0, 0, 0);
        accd[1] = __builtin_amdgcn_mfma_f32_16x16x32_bf16(Ub.v, ones, accd[1], 0, 0, 0);
        __builtin_amdgcn_s_setprio(0);
        cA0 = nA0; cA1 = nA1; cB0 = nB0; cB1 = nB1;
    }

    // pden: accd[rt][r] = row-sum for row i0+rg*32+rt*16+kq*4+r (same value in all m lanes).
    // waves cg=0 (head 0) and cg=2 (head 1) write; lanes m==0 only.
    if ((cg & 1) == 0 && m == 0) {
#pragma unroll
        for (int rt = 0; rt < 2; ++rt)
#pragma unroll
            for (int r = 0; r < 4; ++r) {
                int row = i0 + rg * 32 + rt * 16 + kq * 4 + r;
                pden[((size_t)sidx * NN + row) * 2 + hw] = accd[rt][r];
            }
    }
    size_t pb_ = (size_t)sidx * NN * 256;
#pragma unroll
    for (int rt = 0; rt < 2; ++rt)
#pragma unroll
        for (int r = 0; r < 4; ++r) {
            int row = i0 + rg * 32 + rt * 16 + kq * 4 + r;
#pragma unroll
            for (int f = 0; f < 4; ++f) {
                int col = cg * 64 + f * 16 + m;
                pacc[pb_ + (size_t)row * 256 + col] = f2bf(acc[rt][f][r]);
            }
        }
}

// combine: 8 outputs per thread
__global__ void combine_kernel(const unsigned short* __restrict__ pacc, const float* __restrict__ pden,
                               float* __restrict__ out, int S) {
    size_t idx = ((size_t)blockIdx.x * 256 + threadIdx.x) * 8;
    int i = (int)(idx >> 8);
    int c = (int)(idx & 255);
    int hh = c >> 7;
    float acc[8];
#pragma unroll
    for (int e = 0; e < 8; ++e) acc[e] = 0.f;
    float den = 0.f;
    for (int s = 0; s < S; ++s) {
        uint4 v = *(const uint4*)&pacc[(size_t)s * NN * 256 + idx];
        unsigned int uu[4] = {v.x, v.y, v.z, v.w};
#pragma unroll
        for (int q = 0; q < 4; ++q) {
            acc[2*q]   += bf2f((unsigned short)(uu[q] & 0xffff));
            acc[2*q+1] += bf2f((unsigned short)(uu[q] >> 16));
        }
        den += pden[((size_t)s * NN + i) * 2 + hh];
    }
    float r = 1.f / den;
    float4 o0 = {acc[0]*r, acc[1]*r, acc[2]*r, acc[3]*r};
    float4 o1 = {acc[4]*r, acc[5]*r, acc[6]*r, acc[7]*r};
    *(float4*)&out[idx] = o0;
    *(float4*)&out[idx + 4] = o1;
}

extern "C" void kernel_launch(void* const* d_in, const int* in_sizes, int n_in,
                              void* d_out, int out_size, void* d_ws, size_t ws_size,
                              hipStream_t stream) {
    const float* hmat = (const float*)d_in[0];
    const int*   adj  = (const int*)d_in[1];
    const float* W1   = (const float*)d_in[2];
    const float* b1   = (const float*)d_in[3];
    const float* W2   = (const float*)d_in[4];
    const float* b2   = (const float*)d_in[5];
    const float* W3   = (const float*)d_in[6];
    const float* b3   = (const float*)d_in[7];
    const float* a    = (const float*)d_in[8];
    float* out = (float*)d_out;

    char* p = (char*)d_ws;
    float* v1  = (float*)p; p += 2048;
    float* v2  = (float*)p; p += 2048;
    float* bd  = (float*)p; p += 256;
    float* s1  = (float*)p; p += (size_t)NN * 2 * sizeof(float);
    float* s2h = (float*)p; p += (size_t)NN * 2 * sizeof(float);
    float* v1p = (float*)p; p += 8 * 512 * sizeof(float);
    float* v2p = (float*)p; p += 8 * 512 * sizeof(float);
    unsigned short* w3b = (unsigned short*)p; p += (size_t)NN * 256 * 2;
    const int S = 4;                               // ws ~1 GB observed; 4 partials = 21 MB
    float* pden = (float*)p; p += (size_t)S * NN * 2 * sizeof(float);
    unsigned short* pacc = (unsigned short*)p;

    prep_partial<<<16, 512, 0, stream>>>(W1, W2, a, v1p, v2p);
    prep_reduce<<<1, 512, 0, stream>>>(b1, b2, a, v1p, v2p, v1, v2, bd);
    s_kernel<<<NN / 4, 256, 0, stream>>>(hmat, v1, v2, bd, s1, s2h);
    w3_kernel<<<NN / 32, 128, 0, stream>>>(hmat, W3, b3, w3b);
    int jc = NN / S;
    attn_fused<<<dim3(NN / 64, S), 512, 0, stream>>>(adj, s1, s2h, w3b, pacc, pden, jc);
    combine_kernel<<<(NN * 256) / (256 * 8), 256, 0, stream>>>(pacc, pden, out, S);
}

// Round 8
// 160.292 us; speedup vs baseline: 1.6284x; 1.6284x over previous
//
#include <hip/hip_runtime.h>
#include <hip/hip_bf16.h>

#define NN 8192
#define LOG2E 1.44269504088896f
#define S_SPLIT 8
#define JC 1024
#define NT 32

typedef __attribute__((ext_vector_type(8))) short short8;
typedef __attribute__((ext_vector_type(4))) float f32x4;

static __device__ __forceinline__ float bf2f(unsigned short u) {
    union { unsigned int i; float f; } v; v.i = ((unsigned int)u) << 16; return v.f;
}
static __device__ __forceinline__ unsigned short f2bf(float f) {
    union { float f; unsigned int i; } v; v.f = f;
    unsigned int lsb = (v.i >> 16) & 1u;
    v.i += 0x7fffu + lsb;
    return (unsigned short)(v.i >> 16);
}
static __device__ __forceinline__ unsigned int cvtpk(float lo, float hi) {
    unsigned int r;
    asm("v_cvt_pk_bf16_f32 %0, %1, %2" : "=v"(r) : "v"(lo), "v"(hi));
    return r;
}
static __device__ __forceinline__ float fexp2(float x) { return __builtin_amdgcn_exp2f(x); }

static __device__ __forceinline__ void cvt8(const float* __restrict__ p, short8& hi, short8& lo) {
    float4 u = *(const float4*)p;
    float4 v = *(const float4*)(p + 4);
    float f[8] = {u.x, u.y, u.z, u.w, v.x, v.y, v.z, v.w};
#pragma unroll
    for (int j = 0; j < 8; ++j) {
        unsigned short hb = f2bf(f[j]);
        hi[j] = (short)hb;
        lo[j] = (short)f2bf(f[j] - bf2f(hb));
    }
}

// ---- pack adj (256 MB int32 0/1) -> bitmask (8 MB). Pure streaming pass. ----
__global__ __launch_bounds__(256) void pack_kernel(const int* __restrict__ adj,
                                                   unsigned int* __restrict__ abits) {
    int w = blockIdx.x * 256 + threadIdx.x;      // word index, 2M total (256 words/row)
    const int* src = adj + (size_t)w * 32;
    unsigned int bits = 0;
#pragma unroll
    for (int k = 0; k < 8; ++k) {
        int4 v = *(const int4*)(src + k * 4);
        bits |= (unsigned int)(v.x & 1) << (k * 4 + 0);
        bits |= (unsigned int)(v.y & 1) << (k * 4 + 1);
        bits |= (unsigned int)(v.z & 1) << (k * 4 + 2);
        bits |= (unsigned int)(v.w & 1) << (k * 4 + 3);
    }
    abits[w] = bits;
}

// ---- prep: v1/v2 (W^T a vectors), split over 16 blocks then reduced ----
__global__ void prep_partial(const float* __restrict__ W1, const float* __restrict__ W2,
                             const float* __restrict__ a,
                             float* __restrict__ v1p, float* __restrict__ v2p) {
    int b = blockIdx.x;
    int t = threadIdx.x;
    int hh = t >> 8, k = t & 255;
    int c0 = (b & 7) * 16;
    const float* W = (b < 8) ? W1 : W2;
    int aoff = (b < 8) ? 0 : 128;
    float acc = 0.f;
    for (int c = c0; c < c0 + 16; ++c)
        acc += W[(size_t)(hh * 128 + c) * 256 + k] * a[hh * 256 + aoff + c];
    ((b < 8) ? v1p : v2p)[(b & 7) * 512 + t] = acc;
}

__global__ void prep_reduce(const float* __restrict__ b1, const float* __restrict__ b2,
                            const float* __restrict__ a,
                            const float* __restrict__ v1p, const float* __restrict__ v2p,
                            float* __restrict__ v1, float* __restrict__ v2, float* __restrict__ bd) {
    int t = threadIdx.x;
    float a1 = 0.f, a2 = 0.f;
    for (int b = 0; b < 8; ++b) { a1 += v1p[b * 512 + t]; a2 += v2p[b * 512 + t]; }
    v1[t] = a1;
    v2[t] = a2;
    int g = t >> 7;
    int hh = g >> 1, which = g & 1, c = t & 127;
    float prod = which ? b2[hh * 128 + c] * a[hh * 256 + 128 + c]
                       : b1[hh * 128 + c] * a[hh * 256 + c];
#pragma unroll
    for (int off = 1; off < 64; off <<= 1) prod += __shfl_xor(prod, off);
    __shared__ float ws[8];
    if ((t & 63) == 0) ws[t >> 6] = prod;
    __syncthreads();
    if (t < 4) bd[t] = ws[2 * t] + ws[2 * t + 1];
}

// s1[n][h] interleaved; s2 per-head planes s2h[h][n]. Both pre-scaled by log2(e).
__global__ __launch_bounds__(256) void s_kernel(const float* __restrict__ hmat,
                         const float* __restrict__ v1, const float* __restrict__ v2,
                         const float* __restrict__ bd,
                         float* __restrict__ s1o, float* __restrict__ s2o) {
    int w = threadIdx.x >> 6, l = threadIdx.x & 63;
    int n = blockIdx.x * 4 + w;
    float4 hv  = *(const float4*)(hmat + (size_t)n * 256 + l * 4);
    float4 va0 = *(const float4*)(v1 + l * 4);
    float4 va1 = *(const float4*)(v1 + 256 + l * 4);
    float4 vb0 = *(const float4*)(v2 + l * 4);
    float4 vb1 = *(const float4*)(v2 + 256 + l * 4);
    float s10 = hv.x*va0.x + hv.y*va0.y + hv.z*va0.z + hv.w*va0.w;
    float s11 = hv.x*va1.x + hv.y*va1.y + hv.z*va1.z + hv.w*va1.w;
    float s20 = hv.x*vb0.x + hv.y*vb0.y + hv.z*vb0.z + hv.w*vb0.w;
    float s21 = hv.x*vb1.x + hv.y*vb1.y + hv.z*vb1.z + hv.w*vb1.w;
#pragma unroll
    for (int off = 1; off < 64; off <<= 1) {
        s10 += __shfl_xor(s10, off);
        s11 += __shfl_xor(s11, off);
        s20 += __shfl_xor(s20, off);
        s21 += __shfl_xor(s21, off);
    }
    if (l == 0) {
        s1o[n*2 + 0] = (s10 + bd[0]) * LOG2E;
        s1o[n*2 + 1] = (s11 + bd[2]) * LOG2E;
        s2o[n]       = (s20 + bd[1]) * LOG2E;
        s2o[NN + n]  = (s21 + bd[3]) * LOG2E;
    }
}

// W3 -> bf16 hi/lo planes (once; was redundantly recomputed 256x inside w3_kernel).
__global__ void wcvt_kernel(const float* __restrict__ W3,
                            unsigned short* __restrict__ w3hi, unsigned short* __restrict__ w3lo) {
    int i = blockIdx.x * 256 + threadIdx.x;   // 65536
    float f = W3[i];
    unsigned short hb = f2bf(f);
    w3hi[i] = hb;
    w3lo[i] = f2bf(f - bf2f(hb));
}

// W3h in MFMA-fragment-major layout (w3b), split-bf16 3-MFMA (A from hmat, B preconverted).
// 256 blocks x 256 thr: wave = (rowtile = bIdx*2 + (w&1), colhalf = w>>1 of 8 ct's).
__global__ __launch_bounds__(256) void w3_kernel(const float* __restrict__ hmat,
                                                 const unsigned short* __restrict__ w3hi,
                                                 const unsigned short* __restrict__ w3lo,
                                                 const float* __restrict__ b3,
                                                 unsigned short* __restrict__ w3b) {
    int tid = threadIdx.x;
    int w = tid >> 6, l = tid & 63;
    int m = l & 15, kq = l >> 4;
    int n0 = (blockIdx.x * 2 + (w & 1)) * 16;
    int c0 = (w >> 1) * 8;
    f32x4 acc[8];
#pragma unroll
    for (int ct = 0; ct < 8; ++ct) acc[ct] = (f32x4){0.f, 0.f, 0.f, 0.f};
    for (int k0 = 0; k0 < 256; k0 += 32) {
        short8 ahi, alo;
        cvt8(hmat + (size_t)(n0 + m) * 256 + k0 + kq * 8, ahi, alo);
#pragma unroll
        for (int ct = 0; ct < 8; ++ct) {
            int c = (c0 + ct) * 16 + m;
            short8 bhi = *(const short8*)&w3hi[(size_t)c * 256 + k0 + kq * 8];
            short8 blo = *(const short8*)&w3lo[(size_t)c * 256 + k0 + kq * 8];
            acc[ct] = __builtin_amdgcn_mfma_f32_16x16x32_bf16(ahi, bhi, acc[ct], 0, 0, 0);
            acc[ct] = __builtin_amdgcn_mfma_f32_16x16x32_bf16(alo, bhi, acc[ct], 0, 0, 0);
            acc[ct] = __builtin_amdgcn_mfma_f32_16x16x32_bf16(ahi, blo, acc[ct], 0, 0, 0);
        }
    }
#pragma unroll
    for (int ct = 0; ct < 8; ++ct) {
        int c = (c0 + ct) * 16 + m;
        float bias = b3[c];
#pragma unroll
        for (int e = 0; e < 4; ++e) {
            int n = n0 + kq * 4 + e;
            size_t idx = ((size_t)(n >> 5) * 16 + (c >> 4)) * 512 + (size_t)((((n >> 3) & 3) * 16 + m) * 8 + (n & 7));
            w3b[idx] = f2bf(acc[ct][e] + bias);
        }
    }
}

// ---- main fused attention: fully L2-resident ----
// 256 thr = 4 waves; block = 32 rows x 256 cols (wave wv owns cols wv*64..+64, head wv>>1).
// P computed cooperatively once (thread (r,oct): row r, j's oct*4..+3, both heads), adj as
// bitmask word per (row, 32-j tile). B-frags direct from fragment-major w3b (L2). Denominator
// via ones-B-frag MFMA on even waves. Pt swizzle = round-6 verified scheme.
__global__ __launch_bounds__(256, 6) void attn_fused(
        const unsigned int* __restrict__ abits, const float* __restrict__ s1a,
        const float* __restrict__ s2h, const unsigned short* __restrict__ w3b,
        unsigned short* __restrict__ pacc, float* __restrict__ pden)
{
    __shared__ unsigned short Pt[2][32][32];  // 4 KB
    __shared__ float s2t[2][JC];              // 8 KB

    const int tid = threadIdx.x;
    const int wv = tid >> 6, ln = tid & 63;
    const int m = ln & 15, kq = ln >> 4;
    const int hw = wv >> 1;
    const int r = tid >> 3, oct = tid & 7;
    const int i0 = blockIdx.x * 32;
    const int sidx = blockIdx.y;
    const int j0 = sidx * JC;
    const int sw = kq ^ ((m >> 1) & 3);

    const float s1r0 = s1a[(i0 + r) * 2 + 0];
    const float s1r1 = s1a[(i0 + r) * 2 + 1];
    const unsigned int* abR = abits + (size_t)(i0 + r) * 256 + (j0 >> 5);
    unsigned short* ptw = &Pt[0][0][0] + r * 32 + ((((oct >> 1) ^ ((r >> 1) & 3)) << 3) | ((oct & 1) << 2));
    const unsigned short* pta = &Pt[hw][m][0] + (sw << 3);
    const unsigned short* w3p = w3b + ((size_t)(j0 >> 5) * 16 + wv * 4) * 512 + ln * 8;

    f32x4 acc[2][4];
    f32x4 accd[2];
#pragma unroll
    for (int rt = 0; rt < 2; ++rt) {
        accd[rt] = (f32x4){0.f, 0.f, 0.f, 0.f};
#pragma unroll
        for (int f = 0; f < 4; ++f) acc[rt][f] = (f32x4){0.f, 0.f, 0.f, 0.f};
    }
    short8 ones;
#pragma unroll
    for (int e = 0; e < 8; ++e) ones[e] = (short)0x3F80;

    // prologue: stage s2 planes, first bitmask word
    for (int x = tid; x < 2 * JC; x += 256) {
        int h = x >> 10, j = x & (JC - 1);
        s2t[h][j] = s2h[(size_t)h * NN + j0 + j];
    }
    unsigned int cur = abR[0];
    __syncthreads();

    for (int t = 0; t < NT; ++t) {
        // issue B(t) loads (consumed after the barrier; L2-resident ~200cy, hidden by P-gen)
        const unsigned short* bp = w3p + (size_t)t * 8192;
        short8 bf0 = *(const short8*)(bp);
        short8 bf1 = *(const short8*)(bp + 512);
        short8 bf2 = *(const short8*)(bp + 1024);
        short8 bf3 = *(const short8*)(bp + 1536);
        // prefetch next bitmask word
        unsigned int nxt = abR[(t + 1 < NT) ? t + 1 : t];
        // P-gen: 4 j's x 2 heads
        {
            unsigned int sh = cur >> (oct * 4);
            float4 sv0 = *(const float4*)&s2t[0][t * 32 + oct * 4];
            float4 sv1 = *(const float4*)&s2t[1][t * 32 + oct * 4];
            float x0, q0, q1, q2, q3, u0, u1, u2, u3;
            x0 = s1r0 + sv0.x; x0 = fmaxf(x0, 0.2f * x0); q0 = (sh & 1u) ? fexp2(x0) : 0.f;
            x0 = s1r0 + sv0.y; x0 = fmaxf(x0, 0.2f * x0); q1 = (sh & 2u) ? fexp2(x0) : 0.f;
            x0 = s1r0 + sv0.z; x0 = fmaxf(x0, 0.2f * x0); q2 = (sh & 4u) ? fexp2(x0) : 0.f;
            x0 = s1r0 + sv0.w; x0 = fmaxf(x0, 0.2f * x0); q3 = (sh & 8u) ? fexp2(x0) : 0.f;
            x0 = s1r1 + sv1.x; x0 = fmaxf(x0, 0.2f * x0); u0 = (sh & 1u) ? fexp2(x0) : 0.f;
            x0 = s1r1 + sv1.y; x0 = fmaxf(x0, 0.2f * x0); u1 = (sh & 2u) ? fexp2(x0) : 0.f;
            x0 = s1r1 + sv1.z; x0 = fmaxf(x0, 0.2f * x0); u2 = (sh & 4u) ? fexp2(x0) : 0.f;
            x0 = s1r1 + sv1.w; x0 = fmaxf(x0, 0.2f * x0); u3 = (sh & 8u) ? fexp2(x0) : 0.f;
            uint2 w0 = {cvtpk(q0, q1), cvtpk(q2, q3)};
            uint2 w1 = {cvtpk(u0, u1), cvtpk(u2, u3)};
            *(uint2*)ptw = w0;
            *(uint2*)(ptw + 1024) = w1;
        }
        asm volatile("s_waitcnt lgkmcnt(0)" ::: "memory");
        __builtin_amdgcn_sched_barrier(0);
        __builtin_amdgcn_s_barrier();
        asm volatile("" ::: "memory");
        // MFMA phase: A-frags from Pt (swizzled), B-frags in regs
        {
            short8 a0 = *(const short8*)pta;
            short8 a1 = *(const short8*)(pta + 512);
            __builtin_amdgcn_s_setprio(1);
            acc[0][0] = __builtin_amdgcn_mfma_f32_16x16x32_bf16(a0, bf0, acc[0][0], 0, 0, 0);
            acc[1][0] = __builtin_amdgcn_mfma_f32_16x16x32_bf16(a1, bf0, acc[1][0], 0, 0, 0);
            acc[0][1] = __builtin_amdgcn_mfma_f32_16x16x32_bf16(a0, bf1, acc[0][1], 0, 0, 0);
            acc[1][1] = __builtin_amdgcn_mfma_f32_16x16x32_bf16(a1, bf1, acc[1][1], 0, 0, 0);
            acc[0][2] = __builtin_amdgcn_mfma_f32_16x16x32_bf16(a0, bf2, acc[0][2], 0, 0, 0);
            acc[1][2] = __builtin_amdgcn_mfma_f32_16x16x32_bf16(a1, bf2, acc[1][2], 0, 0, 0);
            acc[0][3] = __builtin_amdgcn_mfma_f32_16x16x32_bf16(a0, bf3, acc[0][3], 0, 0, 0);
            acc[1][3] = __builtin_amdgcn_mfma_f32_16x16x32_bf16(a1, bf3, acc[1][3], 0, 0, 0);
            if ((wv & 1) == 0) {
                accd[0] = __builtin_amdgcn_mfma_f32_16x16x32_bf16(a0, ones, accd[0], 0, 0, 0);
                accd[1] = __builtin_amdgcn_mfma_f32_16x16x32_bf16(a1, ones, accd[1], 0, 0, 0);
            }
            __builtin_amdgcn_s_setprio(0);
        }
        asm volatile("" ::: "memory");
        __builtin_amdgcn_s_barrier();
        asm volatile("" ::: "memory");
        cur = nxt;
    }

    // pden from ones-MFMA accumulators (even waves; all m lanes equal -> m==0 writes)
    if ((wv & 1) == 0 && m == 0) {
#pragma unroll
        for (int rt = 0; rt < 2; ++rt)
#pragma unroll
            for (int e = 0; e < 4; ++e) {
                int row = i0 + rt * 16 + kq * 4 + e;
                pden[((size_t)sidx * NN + row) * 2 + hw] = accd[rt][e];
            }
    }
    size_t pb_ = (size_t)sidx * NN * 256;
#pragma unroll
    for (int rt = 0; rt < 2; ++rt)
#pragma unroll
        for (int e = 0; e < 4; ++e) {
            int row = i0 + rt * 16 + kq * 4 + e;
#pragma unroll
            for (int f = 0; f < 4; ++f) {
                int col = wv * 64 + f * 16 + m;
                pacc[pb_ + (size_t)row * 256 + col] = f2bf(acc[rt][f][e]);
            }
        }
}

// combine: 8 outputs per thread
__global__ void combine_kernel(const unsigned short* __restrict__ pacc, const float* __restrict__ pden,
                               float* __restrict__ out) {
    size_t idx = ((size_t)blockIdx.x * 256 + threadIdx.x) * 8;
    int i = (int)(idx >> 8);
    int c = (int)(idx & 255);
    int hh = c >> 7;
    float acc[8];
#pragma unroll
    for (int e = 0; e < 8; ++e) acc[e] = 0.f;
    float den = 0.f;
    for (int s = 0; s < S_SPLIT; ++s) {
        uint4 v = *(const uint4*)&pacc[(size_t)s * NN * 256 + idx];
        unsigned int uu[4] = {v.x, v.y, v.z, v.w};
#pragma unroll
        for (int q = 0; q < 4; ++q) {
            acc[2*q]   += bf2f((unsigned short)(uu[q] & 0xffff));
            acc[2*q+1] += bf2f((unsigned short)(uu[q] >> 16));
        }
        den += pden[((size_t)s * NN + i) * 2 + hh];
    }
    float r = 1.f / den;
    float4 o0 = {acc[0]*r, acc[1]*r, acc[2]*r, acc[3]*r};
    float4 o1 = {acc[4]*r, acc[5]*r, acc[6]*r, acc[7]*r};
    *(float4*)&out[idx] = o0;
    *(float4*)&out[idx + 4] = o1;
}

extern "C" void kernel_launch(void* const* d_in, const int* in_sizes, int n_in,
                              void* d_out, int out_size, void* d_ws, size_t ws_size,
                              hipStream_t stream) {
    const float* hmat = (const float*)d_in[0];
    const int*   adj  = (const int*)d_in[1];
    const float* W1   = (const float*)d_in[2];
    const float* b1   = (const float*)d_in[3];
    const float* W2   = (const float*)d_in[4];
    const float* b2   = (const float*)d_in[5];
    const float* W3   = (const float*)d_in[6];
    const float* b3   = (const float*)d_in[7];
    const float* a    = (const float*)d_in[8];
    float* out = (float*)d_out;

    char* p = (char*)d_ws;
    float* v1   = (float*)p; p += 2048;
    float* v2   = (float*)p; p += 2048;
    float* bd   = (float*)p; p += 256;
    float* s1   = (float*)p; p += (size_t)NN * 2 * sizeof(float);
    float* s2h  = (float*)p; p += (size_t)NN * 2 * sizeof(float);
    float* v1p  = (float*)p; p += 8 * 512 * sizeof(float);
    float* v2p  = (float*)p; p += 8 * 512 * sizeof(float);
    unsigned short* w3hi = (unsigned short*)p; p += 65536 * 2;
    unsigned short* w3lo = (unsigned short*)p; p += 65536 * 2;
    unsigned short* w3b  = (unsigned short*)p; p += (size_t)NN * 256 * 2;
    unsigned int* abits  = (unsigned int*)p;   p += (size_t)NN * (NN / 32) / 8 * sizeof(unsigned int) * 8; // 8 MB
    float* pden = (float*)p; p += (size_t)S_SPLIT * NN * 2 * sizeof(float);
    unsigned short* pacc = (unsigned short*)p;

    pack_kernel<<<(NN * (NN / 32)) / 256, 256, 0, stream>>>(adj, abits);
    prep_partial<<<16, 512, 0, stream>>>(W1, W2, a, v1p, v2p);
    prep_reduce<<<1, 512, 0, stream>>>(b1, b2, a, v1p, v2p, v1, v2, bd);
    s_kernel<<<NN / 4, 256, 0, stream>>>(hmat, v1, v2, bd, s1, s2h);
    wcvt_kernel<<<256, 256, 0, stream>>>(W3, w3hi, w3lo);
    w3_kernel<<<256, 256, 0, stream>>>(hmat, w3hi, w3lo, b3, w3b);
    attn_fused<<<dim3(NN / 32, S_SPLIT), 256, 0, stream>>>(abits, s1, s2h, w3b, pacc, pden);
    combine_kernel<<<(NN * 256) / (256 * 8), 256, 0, stream>>>(pacc, pden, out);
}